// Round 8
// baseline (420.809 us; speedup 1.0000x reference)
//
#include <hip/hip_runtime.h>

#define FEAT 64
#define HID 10
#define RS 16    // padded row stride (floats) for node tables -> 64B rows
#define EPB 1024 // edges per block in binning passes
#define BSH 6    // 64 nodes per bucket
#define CHK 32   // block-rows per chunk in column-prefix passes
#define AS 13    // LDS row stride (odd -> all 32 banks hit by random dloc)

// ---------- Layer-0 precompute: A = X @ W2[0:64,:], B = X @ W2[64:128,:] ----------
__global__ __launch_bounds__(256) void pre_l0(
    const float* __restrict__ X,    // [NN,64]
    const float* __restrict__ W2,   // [128,10]
    float* __restrict__ A,          // [NP,RS]
    float* __restrict__ B,          // [NP,RS]
    int n_nodes)
{
    __shared__ float w2[128 * 10];
    for (int i = threadIdx.x; i < 1280; i += 256) w2[i] = W2[i];
    __syncthreads();

    int n = blockIdx.x * 256 + threadIdx.x;
    if (n >= n_nodes) return;

    const float4* xr = reinterpret_cast<const float4*>(X + (size_t)n * FEAT);
    float a[10], b[10];
#pragma unroll
    for (int h = 0; h < 10; h++) { a[h] = 0.f; b[h] = 0.f; }

#pragma unroll
    for (int blk = 0; blk < 16; blk++) {
        float4 u = xr[blk];
        float xv[4] = { u.x, u.y, u.z, u.w };
#pragma unroll
        for (int j = 0; j < 4; j++) {
            int k = blk * 4 + j;
#pragma unroll
            for (int h = 0; h < 10; h++) {
                a[h] = fmaf(xv[j], w2[k * 10 + h], a[h]);
                b[h] = fmaf(xv[j], w2[(64 + k) * 10 + h], b[h]);
            }
        }
    }

    float4* Ar = reinterpret_cast<float4*>(A + (size_t)n * RS);
    float4* Br = reinterpret_cast<float4*>(B + (size_t)n * RS);
    Ar[0] = make_float4(a[0], a[1], a[2], a[3]);
    Ar[1] = make_float4(a[4], a[5], a[6], a[7]);
    Ar[2] = make_float4(a[8], a[9], 0.f, 0.f);
    Br[0] = make_float4(b[0], b[1], b[2], b[3]);
    Br[1] = make_float4(b[4], b[5], b[6], b[7]);
    Br[2] = make_float4(b[8], b[9], 0.f, 0.f);
}

// ================= CSR-lite build: bucket-grouped edge list only =================

__global__ __launch_bounds__(256) void bin_hist_k(
    const int* __restrict__ dst, int* __restrict__ blockhist, int n_edges, int nbk)
{
    extern __shared__ int hist[];
    for (int i = threadIdx.x; i < nbk; i += 256) hist[i] = 0;
    __syncthreads();
    int base = blockIdx.x * EPB;
    for (int i = threadIdx.x; i < EPB; i += 256) {
        int e = base + i;
        if (e < n_edges) atomicAdd(&hist[dst[e] >> BSH], 1);
    }
    __syncthreads();
    int* row = blockhist + (size_t)blockIdx.x * nbk;
    for (int i = threadIdx.x; i < nbk; i += 256) row[i] = hist[i];
}

__global__ __launch_bounds__(256) void colchunk_sum_k(
    const int* __restrict__ blockhist, int* __restrict__ chunksum,
    int nbk, int nblk)
{
    int b = blockIdx.x * 256 + threadIdx.x;
    int c = blockIdx.y;
    if (b >= nbk) return;
    int k0 = c * CHK;
    int k1 = min(k0 + CHK, nblk);
    int s = 0;
    for (int k = k0; k < k1; k++) s += blockhist[(size_t)k * nbk + b];
    chunksum[(size_t)c * nbk + b] = s;
}

__global__ __launch_bounds__(256) void chunk_scan_k(
    int* __restrict__ chunksum, int* __restrict__ btot, int nbk, int nchk)
{
    int b = blockIdx.x * 256 + threadIdx.x;
    if (b >= nbk) return;
    int run = 0;
    for (int c = 0; c < nchk; c++) {
        size_t idx = (size_t)c * nbk + b;
        int v = chunksum[idx];
        chunksum[idx] = run;
        run += v;
    }
    btot[b] = run;
}

__global__ __launch_bounds__(256) void scan_k(
    const int* __restrict__ btot, int* __restrict__ bbase,
    int* __restrict__ bucket_start, int nbk, int n_edges)
{
    __shared__ int ts[256];
    int t = threadIdx.x;
    int v[8];
    int s = 0;
#pragma unroll
    for (int j = 0; j < 8; j++) {
        int idx = t * 8 + j;
        v[j] = (idx < nbk) ? btot[idx] : 0;
        s += v[j];
    }
    ts[t] = s;
    __syncthreads();
    for (int off = 1; off < 256; off <<= 1) {
        int x = (t >= off) ? ts[t - off] : 0;
        __syncthreads();
        ts[t] += x;
        __syncthreads();
    }
    int run = ts[t] - s;
#pragma unroll
    for (int j = 0; j < 8; j++) {
        int idx = t * 8 + j;
        if (idx < nbk) { bbase[idx] = run; bucket_start[idx] = run; }
        run += v[j];
    }
    if (t == 255) bucket_start[nbk] = n_edges;
}

__global__ __launch_bounds__(256) void col_off2_k(
    int* __restrict__ blockhist, const int* __restrict__ chunksum,
    const int* __restrict__ bbase, int nbk, int nblk)
{
    int b = blockIdx.x * 256 + threadIdx.x;
    int c = blockIdx.y;
    if (b >= nbk) return;
    int k0 = c * CHK;
    int k1 = min(k0 + CHK, nblk);
    int run = bbase[b] + chunksum[(size_t)c * nbk + b];
    for (int k = k0; k < k1; k++) {
        size_t idx = (size_t)k * nbk + b;
        int v = blockhist[idx];
        blockhist[idx] = run;
        run += v;
    }
}

// Scatter packed (dloc<<17 | src) grouped by bucket; cursors in LDS.
__global__ __launch_bounds__(256) void bin_scatter_k(
    const int* __restrict__ src, const int* __restrict__ dst,
    const int* __restrict__ blockhist, int* __restrict__ packed,
    int n_edges, int nbk)
{
    extern __shared__ int cur[];
    const int* row = blockhist + (size_t)blockIdx.x * nbk;
    for (int i = threadIdx.x; i < nbk; i += 256) cur[i] = row[i];
    __syncthreads();
    int base = blockIdx.x * EPB;
    for (int i = threadIdx.x; i < EPB; i += 256) {
        int e = base + i;
        if (e < n_edges) {
            int d = dst[e];
            int pos = atomicAdd(&cur[d >> BSH], 1);
            packed[pos] = ((d & 63) << 17) | src[e];
        }
    }
}

// ---------- Bucket gather: one block per 64-node bucket; LDS fp32 accumulate ----------
// H[n] = 0.1 * sum_{edges->n} relu(relu(A[n]+B[s]) @ W1)
// Epilogue: LAST ? write H : write A_next = H@W2n[0:10], B_next = H@W2n[10:20].
template<bool LAST>
__global__ __launch_bounds__(256) void bgather_k(
    const float* __restrict__ A,
    const float* __restrict__ B,
    const float* __restrict__ W1,   // [10,10] -> registers
    const float* __restrict__ W2n,  // [20,10] (unused if LAST)
    const int* __restrict__ bstart, // [nbk+1]
    const int* __restrict__ packed, // [NE]
    float* __restrict__ An,         // [NP,RS] (unused if LAST)
    float* __restrict__ Bn,         // [NP,RS] (unused if LAST)
    float* __restrict__ Hout,       // [NP,RS] (used if LAST)
    int n_nodes)
{
    __shared__ float w2[200];
    __shared__ float As[64 * AS];
    __shared__ float acc[64 * AS];

    int t = threadIdx.x;
    if (!LAST) {
        for (int i = t; i < 200; i += 256) w2[i] = W2n[i];
    }
    for (int i = t; i < 64 * AS; i += 256) acc[i] = 0.f;

    // W1 into registers (uniform -> broadcast loads, hoisted out of edge loop)
    float w1r[100];
#pragma unroll
    for (int i = 0; i < 100; i++) w1r[i] = W1[i];

    int bkt = blockIdx.x;
    int node0 = bkt << 6;

    // Stage this bucket's A rows (cols 0..9) into LDS, stride AS.
    for (int i = t; i < 640; i += 256) {
        int r = i / 10, h = i - r * 10;
        As[r * AS + h] = A[(size_t)(node0 + r) * RS + h];
    }
    __syncthreads();

    int base = bstart[bkt];
    int end  = bstart[bkt + 1];
    for (int i = base + t; i < end; i += 256) {
        int p  = packed[i];
        int s  = p & 0x1FFFF;
        int dl = p >> 17;
        const float4* br = reinterpret_cast<const float4*>(B + (size_t)s * RS);
        float4 b0 = br[0], b1 = br[1], b2 = br[2];
        const float* ar = &As[dl * AS];
        float pre[10] = { ar[0] + b0.x, ar[1] + b0.y, ar[2] + b0.z, ar[3] + b0.w,
                          ar[4] + b1.x, ar[5] + b1.y, ar[6] + b1.z, ar[7] + b1.w,
                          ar[8] + b2.x, ar[9] + b2.y };
#pragma unroll
        for (int j = 0; j < 10; j++) pre[j] = fmaxf(pre[j], 0.f);
        float* accd = &acc[dl * AS];
#pragma unroll
        for (int h = 0; h < 10; h++) {
            float z = 0.f;
#pragma unroll
            for (int j = 0; j < 10; j++) z = fmaf(pre[j], w1r[j * 10 + h], z);
            atomicAdd(&accd[h], fmaxf(z, 0.f));   // ds_add_f32
        }
    }
    __syncthreads();

    // Epilogue: 4 threads per node.
    int r = t >> 2;
    int q = t & 3;
    int node = node0 + r;
    if (node >= n_nodes) return;

    if (LAST) {
        // write H row (cols 0..11; 10,11 zeroed)
#pragma unroll
        for (int j = 0; j < 3; j++) {
            int o = q * 3 + j;          // 0..11
            float v = (o < 10) ? acc[r * AS + o] * 0.1f : 0.f;
            if (o < 12) Hout[(size_t)node * RS + o] = v;
        }
    } else {
        float hv[10];
#pragma unroll
        for (int k = 0; k < 10; k++) hv[k] = acc[r * AS + k] * 0.1f;
#pragma unroll
        for (int j = 0; j < 5; j++) {
            int o = q * 5 + j;          // 0..19
            int h   = (o < 10) ? o : o - 10;
            int off = (o < 10) ? 0 : 100;
            float z = 0.f;
#pragma unroll
            for (int k = 0; k < 10; k++) z = fmaf(hv[k], w2[off + k * 10 + h], z);
            float* dstp = (o < 10) ? An : Bn;
            dstp[(size_t)node * RS + h] = z;
        }
    }
}

// ---------- Final node MLP (tiled): out = relu(relu(H@Wf1)@Wf2) ----------
__global__ __launch_bounds__(256) void final_k(
    const float* __restrict__ H,    // [NP,RS]
    const float* __restrict__ Wf1,  // [10,64]
    const float* __restrict__ Wf2,  // [64,64]
    float* __restrict__ out,        // [NN,64]
    int n_nodes)
{
    __shared__ float wf1[640];
    __shared__ float wf2s[64 * 64];
    __shared__ float tT[64 * 64];

    for (int i = threadIdx.x; i < 640; i += 256) wf1[i] = Wf1[i];
    {
        const float4* w2v = reinterpret_cast<const float4*>(Wf2);
        float4* w2s = reinterpret_cast<float4*>(wf2s);
        for (int i = threadIdx.x; i < 1024; i += 256) w2s[i] = w2v[i];
    }

    int node0 = blockIdx.x * 64;

    {
        int r = threadIdx.x & 63;
        int g = threadIdx.x >> 6;
        int node = node0 + r;
        float hv[10];
        if (node < n_nodes) {
            const float4* hr = reinterpret_cast<const float4*>(H + (size_t)node * RS);
            float4 h0 = hr[0], h1 = hr[1], h2 = hr[2];
            hv[0]=h0.x; hv[1]=h0.y; hv[2]=h0.z; hv[3]=h0.w;
            hv[4]=h1.x; hv[5]=h1.y; hv[6]=h1.z; hv[7]=h1.w;
            hv[8]=h2.x; hv[9]=h2.y;
        } else {
#pragma unroll
            for (int k = 0; k < 10; k++) hv[k] = 0.f;
        }
        __syncthreads();
#pragma unroll
        for (int j = 0; j < 16; j++) {
            int c = g * 16 + j;
            float v = 0.f;
#pragma unroll
            for (int k = 0; k < 10; k++) v = fmaf(hv[k], wf1[k * 64 + c], v);
            tT[c * 64 + r] = fmaxf(v, 0.f);
        }
    }
    __syncthreads();

    int r0 = (threadIdx.x >> 4) * 4;
    int c0 = (threadIdx.x & 15) * 4;
    float acc[4][4];
#pragma unroll
    for (int i = 0; i < 4; i++)
#pragma unroll
        for (int j = 0; j < 4; j++) acc[i][j] = 0.f;

    for (int k = 0; k < 64; k++) {
        float4 a = *reinterpret_cast<const float4*>(&tT[k * 64 + r0]);
        float4 b = *reinterpret_cast<const float4*>(&wf2s[k * 64 + c0]);
        float av[4] = { a.x, a.y, a.z, a.w };
        float bv[4] = { b.x, b.y, b.z, b.w };
#pragma unroll
        for (int i = 0; i < 4; i++)
#pragma unroll
            for (int j = 0; j < 4; j++)
                acc[i][j] = fmaf(av[i], bv[j], acc[i][j]);
    }

#pragma unroll
    for (int i = 0; i < 4; i++) {
        int node = node0 + r0 + i;
        if (node < n_nodes) {
            float4 o = make_float4(fmaxf(acc[i][0], 0.f), fmaxf(acc[i][1], 0.f),
                                   fmaxf(acc[i][2], 0.f), fmaxf(acc[i][3], 0.f));
            *reinterpret_cast<float4*>(&out[(size_t)node * FEAT + c0]) = o;
        }
    }
}

extern "C" void kernel_launch(void* const* d_in, const int* in_sizes, int n_in,
                              void* d_out, int out_size, void* d_ws, size_t ws_size,
                              hipStream_t stream) {
    const float* X    = (const float*)d_in[0];
    const float* W2_0 = (const float*)d_in[1];
    const float* W1_0 = (const float*)d_in[2];
    const float* W2_1 = (const float*)d_in[3];
    const float* W1_1 = (const float*)d_in[4];
    const float* W2_2 = (const float*)d_in[5];
    const float* W1_2 = (const float*)d_in[6];
    const float* Wf1  = (const float*)d_in[7];
    const float* Wf2  = (const float*)d_in[8];
    const int* src = (const int*)d_in[9];
    const int* dst = (const int*)d_in[10];
    float* out = (float*)d_out;

    const int n_edges = in_sizes[9];
    const int n_nodes = in_sizes[0] / FEAT;

    const int nbk  = (n_nodes + 63) >> 6;          // buckets (~1563, <=2048 for scan_k)
    const int NP   = nbk << 6;                     // padded node count
    const int nblk = (n_edges + EPB - 1) / EPB;    // binning blocks (~1221)
    const int nchk = (nblk + CHK - 1) / CHK;       // column-prefix chunks (~39)

    const size_t h_elems = (size_t)NP * RS;
    // ws layout (4B elems): H | A0 | B0 | A1 | B1 | packed | blockhist | chunksum | btot | bbase | bstart
    const size_t offH   = 0;
    const size_t offA0  = offH  + h_elems;
    const size_t offB0  = offA0 + h_elems;
    const size_t offA1  = offB0 + h_elems;
    const size_t offB1  = offA1 + h_elems;
    const size_t offPk  = offB1 + h_elems;
    const size_t offBh  = offPk + (size_t)n_edges;
    const size_t offCs  = offBh + (size_t)nblk * nbk;
    const size_t offBt  = offCs + (size_t)nchk * nbk;
    const size_t offBb  = offBt + (size_t)nbk;
    const size_t offBs  = offBb + (size_t)nbk;

    float* H        = (float*)d_ws + offH;
    float* A0       = (float*)d_ws + offA0;
    float* B0       = (float*)d_ws + offB0;
    float* A1       = (float*)d_ws + offA1;
    float* B1       = (float*)d_ws + offB1;
    int* packed     = (int*)d_ws + offPk;
    int* blockhist  = (int*)d_ws + offBh;
    int* chunksum   = (int*)d_ws + offCs;
    int* btot       = (int*)d_ws + offBt;
    int* bbase      = (int*)d_ws + offBb;
    int* bstart     = (int*)d_ws + offBs;

    const int nb = (n_nodes + 255) / 256;
    const int fb = (n_nodes + 63) / 64;
    const int cb = (nbk + 255) / 256;
    const size_t lds_bins = (size_t)nbk * 4;

    // ---- Build bucket-grouped edge list ----
    bin_hist_k<<<nblk, 256, lds_bins, stream>>>(dst, blockhist, n_edges, nbk);
    colchunk_sum_k<<<dim3(cb, nchk), 256, 0, stream>>>(blockhist, chunksum, nbk, nblk);
    chunk_scan_k<<<cb, 256, 0, stream>>>(chunksum, btot, nbk, nchk);
    scan_k<<<1, 256, 0, stream>>>(btot, bbase, bstart, nbk, n_edges);
    col_off2_k<<<dim3(cb, nchk), 256, 0, stream>>>(blockhist, chunksum, bbase, nbk, nblk);
    bin_scatter_k<<<nblk, 256, lds_bins, stream>>>(src, dst, blockhist, packed, n_edges, nbk);

    // ---- Layer 0 precompute + 3 fused gather layers ----
    pre_l0<<<nb, 256, 0, stream>>>(X, W2_0, A0, B0, n_nodes);
    bgather_k<false><<<nbk, 256, 0, stream>>>(A0, B0, W1_0, W2_1, bstart, packed,
                                              A1, B1, nullptr, n_nodes);
    bgather_k<false><<<nbk, 256, 0, stream>>>(A1, B1, W1_1, W2_2, bstart, packed,
                                              A0, B0, nullptr, n_nodes);
    bgather_k<true><<<nbk, 256, 0, stream>>>(A0, B0, W1_2, nullptr, bstart, packed,
                                             nullptr, nullptr, H, n_nodes);

    // ---- Final node MLP ----
    final_k<<<fb, 256, 0, stream>>>(H, Wf1, Wf2, out, n_nodes);
}

// Round 9
// 281.601 us; speedup vs baseline: 1.4943x; 1.4943x over previous
//
#include <hip/hip_runtime.h>

#define FEAT 64
#define HID 10
#define RS 16    // padded row stride (floats) -> 64B rows, one cache line
#define EPB 1024 // edges per block in binning passes (256 thr x 4) -> ~1221 blocks
#define BSH 6    // bucket shift: 64 nodes per bucket
#define CHK 32   // block-rows per chunk in column-prefix passes

// ---------- Layer-0 precompute: A = X @ W2[0:64,:], B = X @ W2[64:128,:] ----------
__global__ __launch_bounds__(256) void pre_l0(
    const float* __restrict__ X,    // [NN,64]
    const float* __restrict__ W2,   // [128,10]
    float* __restrict__ A,          // [NN,RS]
    float* __restrict__ B,          // [NN,RS]
    int n_nodes)
{
    __shared__ float w2[128 * 10];
    for (int i = threadIdx.x; i < 1280; i += 256) w2[i] = W2[i];
    __syncthreads();

    int n = blockIdx.x * 256 + threadIdx.x;
    if (n >= n_nodes) return;

    const float4* xr = reinterpret_cast<const float4*>(X + (size_t)n * FEAT);
    float a[10], b[10];
#pragma unroll
    for (int h = 0; h < 10; h++) { a[h] = 0.f; b[h] = 0.f; }

#pragma unroll
    for (int blk = 0; blk < 16; blk++) {
        float4 u = xr[blk];
        float xv[4] = { u.x, u.y, u.z, u.w };
#pragma unroll
        for (int j = 0; j < 4; j++) {
            int k = blk * 4 + j;
#pragma unroll
            for (int h = 0; h < 10; h++) {
                a[h] = fmaf(xv[j], w2[k * 10 + h], a[h]);
                b[h] = fmaf(xv[j], w2[(64 + k) * 10 + h], b[h]);
            }
        }
    }

    float4* Ar = reinterpret_cast<float4*>(A + (size_t)n * RS);
    float4* Br = reinterpret_cast<float4*>(B + (size_t)n * RS);
    Ar[0] = make_float4(a[0], a[1], a[2], a[3]);
    Ar[1] = make_float4(a[4], a[5], a[6], a[7]);
    Ar[2] = make_float4(a[8], a[9], 0.f, 0.f);
    Br[0] = make_float4(b[0], b[1], b[2], b[3]);
    Br[1] = make_float4(b[4], b[5], b[6], b[7]);
    Br[2] = make_float4(b[8], b[9], 0.f, 0.f);
}

// ---------- Layers 1/2 precompute: A = H @ W2[0:10,:], B = H @ W2[10:20,:] ----------
__global__ __launch_bounds__(256) void pre_small(
    const float* __restrict__ H,    // [NN,RS]
    const float* __restrict__ W2,   // [20,10]
    float* __restrict__ A,          // [NN,RS]
    float* __restrict__ B,          // [NN,RS]
    int n_nodes)
{
    __shared__ float w2[200];
    for (int i = threadIdx.x; i < 200; i += 256) w2[i] = W2[i];
    __syncthreads();

    int n = blockIdx.x * 256 + threadIdx.x;
    if (n >= n_nodes) return;

    const float4* hr = reinterpret_cast<const float4*>(H + (size_t)n * RS);
    float4 h0 = hr[0], h1 = hr[1], h2 = hr[2];
    float hv[10] = { h0.x, h0.y, h0.z, h0.w, h1.x, h1.y, h1.z, h1.w, h2.x, h2.y };

    float a[10], b[10];
#pragma unroll
    for (int h = 0; h < 10; h++) { a[h] = 0.f; b[h] = 0.f; }
#pragma unroll
    for (int k = 0; k < 10; k++) {
#pragma unroll
        for (int h = 0; h < 10; h++) {
            a[h] = fmaf(hv[k], w2[k * 10 + h], a[h]);
            b[h] = fmaf(hv[k], w2[(10 + k) * 10 + h], b[h]);
        }
    }

    float4* Ar = reinterpret_cast<float4*>(A + (size_t)n * RS);
    float4* Br = reinterpret_cast<float4*>(B + (size_t)n * RS);
    Ar[0] = make_float4(a[0], a[1], a[2], a[3]);
    Ar[1] = make_float4(a[4], a[5], a[6], a[7]);
    Ar[2] = make_float4(a[8], a[9], 0.f, 0.f);
    Br[0] = make_float4(b[0], b[1], b[2], b[3]);
    Br[1] = make_float4(b[4], b[5], b[6], b[7]);
    Br[2] = make_float4(b[8], b[9], 0.f, 0.f);
}

// ================= CSR build: two-level counting sort, LDS cursors only =================

__global__ __launch_bounds__(256) void bin_hist_k(
    const int* __restrict__ dst, int* __restrict__ blockhist, int n_edges, int nbk)
{
    extern __shared__ int hist[];
    for (int i = threadIdx.x; i < nbk; i += 256) hist[i] = 0;
    __syncthreads();
    int base = blockIdx.x * EPB;
    for (int i = threadIdx.x; i < EPB; i += 256) {
        int e = base + i;
        if (e < n_edges) atomicAdd(&hist[dst[e] >> BSH], 1);
    }
    __syncthreads();
    int* row = blockhist + (size_t)blockIdx.x * nbk;
    for (int i = threadIdx.x; i < nbk; i += 256) row[i] = hist[i];
}

__global__ __launch_bounds__(256) void colchunk_sum_k(
    const int* __restrict__ blockhist, int* __restrict__ chunksum,
    int nbk, int nblk)
{
    int b = blockIdx.x * 256 + threadIdx.x;
    int c = blockIdx.y;
    if (b >= nbk) return;
    int k0 = c * CHK;
    int k1 = min(k0 + CHK, nblk);
    int s = 0;
    for (int k = k0; k < k1; k++) s += blockhist[(size_t)k * nbk + b];
    chunksum[(size_t)c * nbk + b] = s;
}

__global__ __launch_bounds__(256) void chunk_scan_k(
    int* __restrict__ chunksum, int* __restrict__ btot, int nbk, int nchk)
{
    int b = blockIdx.x * 256 + threadIdx.x;
    if (b >= nbk) return;
    int run = 0;
    for (int c = 0; c < nchk; c++) {
        size_t idx = (size_t)c * nbk + b;
        int v = chunksum[idx];
        chunksum[idx] = run;
        run += v;
    }
    btot[b] = run;
}

__global__ __launch_bounds__(256) void scan_k(
    const int* __restrict__ btot, int* __restrict__ bbase,
    int* __restrict__ bucket_start, int* __restrict__ start,
    int nbk, int n_nodes, int n_edges)
{
    __shared__ int ts[256];
    int t = threadIdx.x;
    int v[8];
    int s = 0;
#pragma unroll
    for (int j = 0; j < 8; j++) {
        int idx = t * 8 + j;
        v[j] = (idx < nbk) ? btot[idx] : 0;
        s += v[j];
    }
    ts[t] = s;
    __syncthreads();
    for (int off = 1; off < 256; off <<= 1) {
        int x = (t >= off) ? ts[t - off] : 0;
        __syncthreads();
        ts[t] += x;
        __syncthreads();
    }
    int run = ts[t] - s;
#pragma unroll
    for (int j = 0; j < 8; j++) {
        int idx = t * 8 + j;
        if (idx < nbk) { bbase[idx] = run; bucket_start[idx] = run; }
        run += v[j];
    }
    if (t == 255) { bucket_start[nbk] = n_edges; start[n_nodes] = n_edges; }
}

__global__ __launch_bounds__(256) void col_off2_k(
    int* __restrict__ blockhist, const int* __restrict__ chunksum,
    const int* __restrict__ bbase, int nbk, int nblk)
{
    int b = blockIdx.x * 256 + threadIdx.x;
    int c = blockIdx.y;
    if (b >= nbk) return;
    int k0 = c * CHK;
    int k1 = min(k0 + CHK, nblk);
    int run = bbase[b] + chunksum[(size_t)c * nbk + b];
    for (int k = k0; k < k1; k++) {
        size_t idx = (size_t)k * nbk + b;
        int v = blockhist[idx];
        blockhist[idx] = run;
        run += v;
    }
}

__global__ __launch_bounds__(256) void bin_scatter_k(
    const int* __restrict__ src, const int* __restrict__ dst,
    const int* __restrict__ blockhist, int* __restrict__ packed,
    int n_edges, int nbk)
{
    extern __shared__ int cur[];
    const int* row = blockhist + (size_t)blockIdx.x * nbk;
    for (int i = threadIdx.x; i < nbk; i += 256) cur[i] = row[i];
    __syncthreads();
    int base = blockIdx.x * EPB;
    for (int i = threadIdx.x; i < EPB; i += 256) {
        int e = base + i;
        if (e < n_edges) {
            int d = dst[e];
            int pos = atomicAdd(&cur[d >> BSH], 1);
            packed[pos] = ((d & 63) << 17) | src[e];
        }
    }
}

__global__ __launch_bounds__(256) void csr_k(
    const int* __restrict__ packed, const int* __restrict__ bucket_start,
    int* __restrict__ nbr, int* __restrict__ start, int n_nodes)
{
    __shared__ int hist[64];
    __shared__ int excl[64];
    __shared__ int cur[64];
    int b = blockIdx.x;
    int base = bucket_start[b];
    int end  = bucket_start[b + 1];
    if (threadIdx.x < 64) hist[threadIdx.x] = 0;
    __syncthreads();
    for (int i = base + threadIdx.x; i < end; i += 256)
        atomicAdd(&hist[packed[i] >> 17], 1);
    __syncthreads();
    if (threadIdx.x == 0) {
        int r = 0;
        for (int k = 0; k < 64; k++) { excl[k] = r; r += hist[k]; }
    }
    __syncthreads();
    if (threadIdx.x < 64) {
        cur[threadIdx.x] = excl[threadIdx.x];
        int node = (b << 6) + threadIdx.x;
        if (node < n_nodes) start[node] = base + excl[threadIdx.x];
    }
    __syncthreads();
    for (int i = base + threadIdx.x; i < end; i += 256) {
        int p = packed[i];
        int pos = base + atomicAdd(&cur[p >> 17], 1);
        nbr[pos] = p & 0x1FFFF;
    }
}

// ---------- Gather-aggregate (quad-per-node, W1 in SGPRs, zero LDS) ----------
// H[n] = 0.1 * sum_in relu(relu(A[n]+B[s]) @ W1)
__global__ __launch_bounds__(256) void gather_k(
    const float* __restrict__ A,
    const float* __restrict__ B,
    const float* __restrict__ W1,   // [10,10] -> uniform loads -> SGPRs
    const int* __restrict__ start,  // [NN+1]
    const int* __restrict__ nbr,    // [NE] src ids grouped by dst
    float* __restrict__ H,          // [NN,RS]
    int n_nodes)
{
    // Uniform address + constant indices -> compiler emits s_load (SGPR file).
    float w1r[100];
#pragma unroll
    for (int i = 0; i < 100; i++) w1r[i] = W1[i];

    int t = blockIdx.x * 256 + threadIdx.x;
    int n = t >> 2;
    int q = t & 3;
    if (n >= n_nodes) return;

    const float4* ar = reinterpret_cast<const float4*>(A + (size_t)n * RS);
    float4 a0 = ar[0], a1 = ar[1], a2 = ar[2];
    float av[10] = { a0.x, a0.y, a0.z, a0.w, a1.x, a1.y, a1.z, a1.w, a2.x, a2.y };

    float acc[10];
#pragma unroll
    for (int h = 0; h < 10; h++) acc[h] = 0.f;

    int beg = start[n];
    int end = start[n + 1];
    for (int i = beg + q; i < end; i += 4) {
        int s = nbr[i];
        const float4* br = reinterpret_cast<const float4*>(B + (size_t)s * RS);
        float4 b0 = br[0], b1 = br[1], b2 = br[2];
        float pre[10] = { av[0] + b0.x, av[1] + b0.y, av[2] + b0.z, av[3] + b0.w,
                          av[4] + b1.x, av[5] + b1.y, av[6] + b1.z, av[7] + b1.w,
                          av[8] + b2.x, av[9] + b2.y };
#pragma unroll
        for (int j = 0; j < 10; j++) pre[j] = fmaxf(pre[j], 0.f);
#pragma unroll
        for (int h = 0; h < 10; h++) {
            float z = 0.f;
#pragma unroll
            for (int j = 0; j < 10; j++) z = fmaf(pre[j], w1r[j * 10 + h], z);
            acc[h] += fmaxf(z, 0.f);
        }
    }

#pragma unroll
    for (int h = 0; h < 10; h++) acc[h] += __shfl_xor(acc[h], 1);
#pragma unroll
    for (int h = 0; h < 10; h++) acc[h] += __shfl_xor(acc[h], 2);

    if (q == 0) {
        float4* Hr = reinterpret_cast<float4*>(H + (size_t)n * RS);
        Hr[0] = make_float4(acc[0] * 0.1f, acc[1] * 0.1f, acc[2] * 0.1f, acc[3] * 0.1f);
        Hr[1] = make_float4(acc[4] * 0.1f, acc[5] * 0.1f, acc[6] * 0.1f, acc[7] * 0.1f);
        Hr[2] = make_float4(acc[8] * 0.1f, acc[9] * 0.1f, 0.f, 0.f);
    }
}

// ---------- Final node MLP (tiled): out = relu(relu(H@Wf1)@Wf2) ----------
__global__ __launch_bounds__(256) void final_k(
    const float* __restrict__ H,    // [NN,RS]
    const float* __restrict__ Wf1,  // [10,64]
    const float* __restrict__ Wf2,  // [64,64]
    float* __restrict__ out,        // [NN,64]
    int n_nodes)
{
    __shared__ float wf1[640];
    __shared__ float wf2s[64 * 64];
    __shared__ float tT[64 * 64];

    for (int i = threadIdx.x; i < 640; i += 256) wf1[i] = Wf1[i];
    {
        const float4* w2v = reinterpret_cast<const float4*>(Wf2);
        float4* w2s = reinterpret_cast<float4*>(wf2s);
        for (int i = threadIdx.x; i < 1024; i += 256) w2s[i] = w2v[i];
    }

    int node0 = blockIdx.x * 64;

    {
        int r = threadIdx.x & 63;
        int g = threadIdx.x >> 6;
        int node = node0 + r;
        float hv[10];
        if (node < n_nodes) {
            const float4* hr = reinterpret_cast<const float4*>(H + (size_t)node * RS);
            float4 h0 = hr[0], h1 = hr[1], h2 = hr[2];
            hv[0]=h0.x; hv[1]=h0.y; hv[2]=h0.z; hv[3]=h0.w;
            hv[4]=h1.x; hv[5]=h1.y; hv[6]=h1.z; hv[7]=h1.w;
            hv[8]=h2.x; hv[9]=h2.y;
        } else {
#pragma unroll
            for (int k = 0; k < 10; k++) hv[k] = 0.f;
        }
        __syncthreads();
#pragma unroll
        for (int j = 0; j < 16; j++) {
            int c = g * 16 + j;
            float v = 0.f;
#pragma unroll
            for (int k = 0; k < 10; k++) v = fmaf(hv[k], wf1[k * 64 + c], v);
            tT[c * 64 + r] = fmaxf(v, 0.f);
        }
    }
    __syncthreads();

    int r0 = (threadIdx.x >> 4) * 4;
    int c0 = (threadIdx.x & 15) * 4;
    float acc[4][4];
#pragma unroll
    for (int i = 0; i < 4; i++)
#pragma unroll
        for (int j = 0; j < 4; j++) acc[i][j] = 0.f;

    for (int k = 0; k < 64; k++) {
        float4 a = *reinterpret_cast<const float4*>(&tT[k * 64 + r0]);
        float4 b = *reinterpret_cast<const float4*>(&wf2s[k * 64 + c0]);
        float av[4] = { a.x, a.y, a.z, a.w };
        float bv[4] = { b.x, b.y, b.z, b.w };
#pragma unroll
        for (int i = 0; i < 4; i++)
#pragma unroll
            for (int j = 0; j < 4; j++)
                acc[i][j] = fmaf(av[i], bv[j], acc[i][j]);
    }

#pragma unroll
    for (int i = 0; i < 4; i++) {
        int node = node0 + r0 + i;
        if (node < n_nodes) {
            float4 o = make_float4(fmaxf(acc[i][0], 0.f), fmaxf(acc[i][1], 0.f),
                                   fmaxf(acc[i][2], 0.f), fmaxf(acc[i][3], 0.f));
            *reinterpret_cast<float4*>(&out[(size_t)node * FEAT + c0]) = o;
        }
    }
}

extern "C" void kernel_launch(void* const* d_in, const int* in_sizes, int n_in,
                              void* d_out, int out_size, void* d_ws, size_t ws_size,
                              hipStream_t stream) {
    const float* X    = (const float*)d_in[0];
    const float* W2_0 = (const float*)d_in[1];
    const float* W1_0 = (const float*)d_in[2];
    const float* W2_1 = (const float*)d_in[3];
    const float* W1_1 = (const float*)d_in[4];
    const float* W2_2 = (const float*)d_in[5];
    const float* W1_2 = (const float*)d_in[6];
    const float* Wf1  = (const float*)d_in[7];
    const float* Wf2  = (const float*)d_in[8];
    const int* src = (const int*)d_in[9];
    const int* dst = (const int*)d_in[10];
    float* out = (float*)d_out;

    const int n_edges = in_sizes[9];
    const int n_nodes = in_sizes[0] / FEAT;

    const int nbk  = (n_nodes + 63) >> 6;          // coarse buckets (<=2048 for scan_k)
    const int nblk = (n_edges + EPB - 1) / EPB;    // binning blocks (~1221)
    const int nchk = (nblk + CHK - 1) / CHK;       // column-prefix chunks (~39)

    const size_t h_elems = (size_t)n_nodes * RS;
    // ws layout (4B elems): H | A | B | nbr | packed | blockhist | chunksum | btot | bbase | bstart | start
    const size_t offH   = 0;
    const size_t offA   = offH + h_elems;
    const size_t offB   = offA + h_elems;
    const size_t offNbr = offB + h_elems;
    const size_t offPk  = offNbr + (size_t)n_edges;
    const size_t offBh  = offPk + (size_t)n_edges;
    const size_t offCs  = offBh + (size_t)nblk * nbk;
    const size_t offBt  = offCs + (size_t)nchk * nbk;
    const size_t offBb  = offBt + (size_t)nbk;
    const size_t offBs  = offBb + (size_t)nbk;
    const size_t offSt  = offBs + (size_t)nbk + 1;

    float* H        = (float*)d_ws + offH;
    float* A        = (float*)d_ws + offA;
    float* B        = (float*)d_ws + offB;
    int* nbr        = (int*)d_ws + offNbr;
    int* packed     = (int*)d_ws + offPk;
    int* blockhist  = (int*)d_ws + offBh;
    int* chunksum   = (int*)d_ws + offCs;
    int* btot       = (int*)d_ws + offBt;
    int* bbase      = (int*)d_ws + offBb;
    int* bstart     = (int*)d_ws + offBs;
    int* start      = (int*)d_ws + offSt;

    const int nb = (n_nodes + 255) / 256;
    const int gb = (n_nodes * 4 + 255) / 256;
    const int fb = (n_nodes + 63) / 64;
    const int cb = (nbk + 255) / 256;
    const size_t lds_bins = (size_t)nbk * 4;

    // ---- CSR build (two-level counting sort; LDS cursors; parallel column prefix) ----
    bin_hist_k<<<nblk, 256, lds_bins, stream>>>(dst, blockhist, n_edges, nbk);
    colchunk_sum_k<<<dim3(cb, nchk), 256, 0, stream>>>(blockhist, chunksum, nbk, nblk);
    chunk_scan_k<<<cb, 256, 0, stream>>>(chunksum, btot, nbk, nchk);
    scan_k<<<1, 256, 0, stream>>>(btot, bbase, bstart, start, nbk, n_nodes, n_edges);
    col_off2_k<<<dim3(cb, nchk), 256, 0, stream>>>(blockhist, chunksum, bbase, nbk, nblk);
    bin_scatter_k<<<nblk, 256, lds_bins, stream>>>(src, dst, blockhist, packed, n_edges, nbk);
    csr_k<<<nbk, 256, 0, stream>>>(packed, bstart, nbr, start, n_nodes);

    // ---- Layer 0 ----
    pre_l0<<<nb, 256, 0, stream>>>(X, W2_0, A, B, n_nodes);
    gather_k<<<gb, 256, 0, stream>>>(A, B, W1_0, start, nbr, H, n_nodes);

    // ---- Layer 1 ----
    pre_small<<<nb, 256, 0, stream>>>(H, W2_1, A, B, n_nodes);
    gather_k<<<gb, 256, 0, stream>>>(A, B, W1_1, start, nbr, H, n_nodes);

    // ---- Layer 2 ----
    pre_small<<<nb, 256, 0, stream>>>(H, W2_2, A, B, n_nodes);
    gather_k<<<gb, 256, 0, stream>>>(A, B, W1_2, start, nbr, H, n_nodes);

    // ---- Final node MLP ----
    final_k<<<fb, 256, 0, stream>>>(H, Wf1, Wf2, out, n_nodes);
}

// Round 10
// 249.985 us; speedup vs baseline: 1.6833x; 1.1265x over previous
//
#include <hip/hip_runtime.h>
#include <hip/hip_bf16.h>

#define FEAT 64
#define HID 10
#define RS 16    // fp32 row stride (floats) -> 64B rows
#define BRS 8    // packed-bf16 B row stride (dwords) -> 32B rows
#define EPB 1024 // edges per block in binning passes -> ~1221 blocks
#define BSH 6    // bucket shift: 64 nodes per bucket
#define CHK 32   // block-rows per chunk in column-prefix passes

typedef __attribute__((ext_vector_type(2))) float f32x2;

#if defined(__has_builtin)
#if __has_builtin(__builtin_elementwise_fma)
#define HAVE_EW_FMA 1
#endif
#endif

__device__ __forceinline__ f32x2 pk_fma(f32x2 a, f32x2 b, f32x2 c) {
#ifdef HAVE_EW_FMA
    return __builtin_elementwise_fma(a, b, c);
#else
    f32x2 r; r.x = fmaf(a.x, b.x, c.x); r.y = fmaf(a.y, b.y, c.y); return r;
#endif
}
__device__ __forceinline__ f32x2 pk_max0(f32x2 a) {
    f32x2 r; r.x = fmaxf(a.x, 0.f); r.y = fmaxf(a.y, 0.f); return r;
}
__device__ __forceinline__ float bflo(unsigned int u) { return __uint_as_float(u << 16); }
__device__ __forceinline__ float bfhi(unsigned int u) { return __uint_as_float(u & 0xffff0000u); }
__device__ __forceinline__ unsigned int packbf2(float lo, float hi) {
    __hip_bfloat16 l = __float2bfloat16(lo);
    __hip_bfloat16 h = __float2bfloat16(hi);
    unsigned short ls = *reinterpret_cast<unsigned short*>(&l);
    unsigned short hs = *reinterpret_cast<unsigned short*>(&h);
    return ((unsigned int)hs << 16) | ls;
}

// ---------- Layer-0 precompute: A=X@W2[0:64,:] (fp32), B=X@W2[64:128,:] (bf16 packed) ----------
__global__ __launch_bounds__(256) void pre_l0(
    const float* __restrict__ X,    // [NN,64]
    const float* __restrict__ W2,   // [128,10]
    float* __restrict__ A,          // [NN,RS] fp32
    unsigned int* __restrict__ Bt,  // [NN,BRS] packed bf16x2
    int n_nodes)
{
    __shared__ float w2[128 * 10];
    for (int i = threadIdx.x; i < 1280; i += 256) w2[i] = W2[i];
    __syncthreads();

    int n = blockIdx.x * 256 + threadIdx.x;
    if (n >= n_nodes) return;

    const float4* xr = reinterpret_cast<const float4*>(X + (size_t)n * FEAT);
    float a[10], b[10];
#pragma unroll
    for (int h = 0; h < 10; h++) { a[h] = 0.f; b[h] = 0.f; }

#pragma unroll
    for (int blk = 0; blk < 16; blk++) {
        float4 u = xr[blk];
        float xv[4] = { u.x, u.y, u.z, u.w };
#pragma unroll
        for (int j = 0; j < 4; j++) {
            int k = blk * 4 + j;
#pragma unroll
            for (int h = 0; h < 10; h++) {
                a[h] = fmaf(xv[j], w2[k * 10 + h], a[h]);
                b[h] = fmaf(xv[j], w2[(64 + k) * 10 + h], b[h]);
            }
        }
    }

    float4* Ar = reinterpret_cast<float4*>(A + (size_t)n * RS);
    Ar[0] = make_float4(a[0], a[1], a[2], a[3]);
    Ar[1] = make_float4(a[4], a[5], a[6], a[7]);
    Ar[2] = make_float4(a[8], a[9], 0.f, 0.f);
    unsigned int bp[5];
#pragma unroll
    for (int j = 0; j < 5; j++) bp[j] = packbf2(b[2 * j], b[2 * j + 1]);
    uint4* Br = reinterpret_cast<uint4*>(Bt + (size_t)n * BRS);
    Br[0] = make_uint4(bp[0], bp[1], bp[2], bp[3]);
    Bt[(size_t)n * BRS + 4] = bp[4];
}

// ================= CSR build: two-level counting sort, LDS cursors only =================

__global__ __launch_bounds__(256) void bin_hist_k(
    const int* __restrict__ dst, int* __restrict__ blockhist, int n_edges, int nbk)
{
    extern __shared__ int hist[];
    for (int i = threadIdx.x; i < nbk; i += 256) hist[i] = 0;
    __syncthreads();
    int base = blockIdx.x * EPB;
    for (int i = threadIdx.x; i < EPB; i += 256) {
        int e = base + i;
        if (e < n_edges) atomicAdd(&hist[dst[e] >> BSH], 1);
    }
    __syncthreads();
    int* row = blockhist + (size_t)blockIdx.x * nbk;
    for (int i = threadIdx.x; i < nbk; i += 256) row[i] = hist[i];
}

// chunksum is stored TRANSPOSED: chunksum[b * nchk + c]
__global__ __launch_bounds__(256) void colchunk_sum_k(
    const int* __restrict__ blockhist, int* __restrict__ chunksum,
    int nbk, int nblk, int nchk)
{
    int b = blockIdx.x * 256 + threadIdx.x;
    int c = blockIdx.y;
    if (b >= nbk) return;
    int k0 = c * CHK;
    int k1 = min(k0 + CHK, nblk);
    int s = 0;
    for (int k = k0; k < k1; k++) s += blockhist[(size_t)k * nbk + b];
    chunksum[(size_t)b * nchk + c] = s;
}

__global__ __launch_bounds__(256) void chunk_scan_k(
    int* __restrict__ chunksum, int* __restrict__ btot, int nbk, int nchk)
{
    int b = blockIdx.x * 256 + threadIdx.x;
    if (b >= nbk) return;
    int run = 0;
    int* row = chunksum + (size_t)b * nchk;   // contiguous walk (L1-resident)
    for (int c = 0; c < nchk; c++) {
        int v = row[c];
        row[c] = run;
        run += v;
    }
    btot[b] = run;
}

__global__ __launch_bounds__(256) void scan_k(
    const int* __restrict__ btot, int* __restrict__ bbase,
    int* __restrict__ bucket_start, int* __restrict__ start,
    int nbk, int n_nodes, int n_edges)
{
    __shared__ int ts[256];
    int t = threadIdx.x;
    int v[8];
    int s = 0;
#pragma unroll
    for (int j = 0; j < 8; j++) {
        int idx = t * 8 + j;
        v[j] = (idx < nbk) ? btot[idx] : 0;
        s += v[j];
    }
    ts[t] = s;
    __syncthreads();
    for (int off = 1; off < 256; off <<= 1) {
        int x = (t >= off) ? ts[t - off] : 0;
        __syncthreads();
        ts[t] += x;
        __syncthreads();
    }
    int run = ts[t] - s;
#pragma unroll
    for (int j = 0; j < 8; j++) {
        int idx = t * 8 + j;
        if (idx < nbk) { bbase[idx] = run; bucket_start[idx] = run; }
        run += v[j];
    }
    if (t == 255) { bucket_start[nbk] = n_edges; start[n_nodes] = n_edges; }
}

__global__ __launch_bounds__(256) void col_off2_k(
    int* __restrict__ blockhist, const int* __restrict__ chunksum,
    const int* __restrict__ bbase, int nbk, int nblk, int nchk)
{
    int b = blockIdx.x * 256 + threadIdx.x;
    int c = blockIdx.y;
    if (b >= nbk) return;
    int k0 = c * CHK;
    int k1 = min(k0 + CHK, nblk);
    int run = bbase[b] + chunksum[(size_t)b * nchk + c];
    for (int k = k0; k < k1; k++) {
        size_t idx = (size_t)k * nbk + b;
        int v = blockhist[idx];
        blockhist[idx] = run;
        run += v;
    }
}

__global__ __launch_bounds__(256) void bin_scatter_k(
    const int* __restrict__ src, const int* __restrict__ dst,
    const int* __restrict__ blockhist, int* __restrict__ packed,
    int n_edges, int nbk)
{
    extern __shared__ int cur[];
    const int* row = blockhist + (size_t)blockIdx.x * nbk;
    for (int i = threadIdx.x; i < nbk; i += 256) cur[i] = row[i];
    __syncthreads();
    int base = blockIdx.x * EPB;
    for (int i = threadIdx.x; i < EPB; i += 256) {
        int e = base + i;
        if (e < n_edges) {
            int d = dst[e];
            int pos = atomicAdd(&cur[d >> BSH], 1);
            packed[pos] = ((d & 63) << 17) | src[e];
        }
    }
}

__global__ __launch_bounds__(256) void csr_k(
    const int* __restrict__ packed, const int* __restrict__ bucket_start,
    int* __restrict__ nbr, int* __restrict__ start, int n_nodes)
{
    __shared__ int hist[64];
    __shared__ int excl[64];
    __shared__ int cur[64];
    int b = blockIdx.x;
    int base = bucket_start[b];
    int end  = bucket_start[b + 1];
    if (threadIdx.x < 64) hist[threadIdx.x] = 0;
    __syncthreads();
    for (int i = base + threadIdx.x; i < end; i += 256)
        atomicAdd(&hist[packed[i] >> 17], 1);
    __syncthreads();
    if (threadIdx.x == 0) {
        int r = 0;
        for (int k = 0; k < 64; k++) { excl[k] = r; r += hist[k]; }
    }
    __syncthreads();
    if (threadIdx.x < 64) {
        cur[threadIdx.x] = excl[threadIdx.x];
        int node = (b << 6) + threadIdx.x;
        if (node < n_nodes) start[node] = base + excl[threadIdx.x];
    }
    __syncthreads();
    for (int i = base + threadIdx.x; i < end; i += 256) {
        int p = packed[i];
        int pos = base + atomicAdd(&cur[p >> 17], 1);
        nbr[pos] = p & 0x1FFFF;
    }
}

// ---------- Gather-aggregate (quad-per-node, packed-pair FMA, fused next-layer pre) ----------
// h = 0.1 * sum_in relu(relu(A[n] + B[s]) @ W1)
// LAST ? Hout[n] = h : { An[n] = h@W2n[0:10], Bn[n] = pack_bf16(h@W2n[10:20]) }
template<bool LAST>
__global__ __launch_bounds__(256) void gather_k(
    const float* __restrict__ A,           // [NN,RS] fp32
    const unsigned int* __restrict__ Bt,   // [NN,BRS] packed bf16x2
    const float* __restrict__ W1,          // [10,10] -> SGPR pairs
    const float* __restrict__ W2n,         // [20,10] (LDS; unused if LAST)
    const int* __restrict__ start,         // [NN+1]
    const int* __restrict__ nbr,           // [NE]
    float* __restrict__ An,                // fp32 next-A (unused if LAST)
    unsigned int* __restrict__ Bn,         // packed next-B (unused if LAST)
    float* __restrict__ Hout,              // fp32 H (used if LAST)
    int n_nodes)
{
    __shared__ float w2s[200];
    if (!LAST) {
        for (int i = threadIdx.x; i < 200; i += 256) w2s[i] = W2n[i];
        __syncthreads();
    }

    // W1 as float2 pairs; uniform loads -> SGPRs.
    f32x2 w1p[10][5];
#pragma unroll
    for (int j = 0; j < 10; j++)
#pragma unroll
        for (int h2 = 0; h2 < 5; h2++)
            w1p[j][h2] = (f32x2){ W1[j * 10 + 2 * h2], W1[j * 10 + 2 * h2 + 1] };

    int t = blockIdx.x * 256 + threadIdx.x;
    int n = t >> 2;
    int q = t & 3;
    if (n >= n_nodes) return;

    const float4* ar = reinterpret_cast<const float4*>(A + (size_t)n * RS);
    float4 a0 = ar[0], a1 = ar[1], a2 = ar[2];
    f32x2 av2[5] = { {a0.x,a0.y}, {a0.z,a0.w}, {a1.x,a1.y}, {a1.z,a1.w}, {a2.x,a2.y} };

    f32x2 acc2[5];
#pragma unroll
    for (int h2 = 0; h2 < 5; h2++) acc2[h2] = (f32x2){0.f, 0.f};

    int beg = start[n];
    int end = start[n + 1];
    for (int i = beg + q; i < end; i += 4) {
        int s = nbr[i];
        const uint4* bp = reinterpret_cast<const uint4*>(Bt + (size_t)s * BRS);
        uint4 u = bp[0];
        unsigned int u4 = Bt[(size_t)s * BRS + 4];
        f32x2 pre[5];
        pre[0] = av2[0] + (f32x2){ bflo(u.x), bfhi(u.x) };
        pre[1] = av2[1] + (f32x2){ bflo(u.y), bfhi(u.y) };
        pre[2] = av2[2] + (f32x2){ bflo(u.z), bfhi(u.z) };
        pre[3] = av2[3] + (f32x2){ bflo(u.w), bfhi(u.w) };
        pre[4] = av2[4] + (f32x2){ bflo(u4),  bfhi(u4)  };
#pragma unroll
        for (int k = 0; k < 5; k++) pre[k] = pk_max0(pre[k]);

        f32x2 z[5];
#pragma unroll
        for (int h2 = 0; h2 < 5; h2++) z[h2] = (f32x2){0.f, 0.f};
#pragma unroll
        for (int j2 = 0; j2 < 5; j2++) {
            f32x2 pa = (f32x2){ pre[j2].x, pre[j2].x };
            f32x2 pb = (f32x2){ pre[j2].y, pre[j2].y };
#pragma unroll
            for (int h2 = 0; h2 < 5; h2++) {
                z[h2] = pk_fma(pa, w1p[2 * j2][h2], z[h2]);
                z[h2] = pk_fma(pb, w1p[2 * j2 + 1][h2], z[h2]);
            }
        }
#pragma unroll
        for (int h2 = 0; h2 < 5; h2++) acc2[h2] += pk_max0(z[h2]);
    }

    // quad reduction: after xor1+xor2 ALL 4 lanes hold the full sum
#pragma unroll
    for (int h2 = 0; h2 < 5; h2++) {
        acc2[h2].x += __shfl_xor(acc2[h2].x, 1);
        acc2[h2].y += __shfl_xor(acc2[h2].y, 1);
    }
#pragma unroll
    for (int h2 = 0; h2 < 5; h2++) {
        acc2[h2].x += __shfl_xor(acc2[h2].x, 2);
        acc2[h2].y += __shfl_xor(acc2[h2].y, 2);
    }

    float hv[10];
#pragma unroll
    for (int h2 = 0; h2 < 5; h2++) {
        hv[2 * h2]     = acc2[h2].x * 0.1f;
        hv[2 * h2 + 1] = acc2[h2].y * 0.1f;
    }

    if (LAST) {
        float* Hr = Hout + (size_t)n * RS;
        if (q == 0)      *reinterpret_cast<float4*>(Hr)     = make_float4(hv[0], hv[1], hv[2], hv[3]);
        else if (q == 1) *reinterpret_cast<float4*>(Hr + 4) = make_float4(hv[4], hv[5], hv[6], hv[7]);
        else if (q == 2) *reinterpret_cast<float2*>(Hr + 8) = make_float2(hv[8], hv[9]);
    } else {
        if (q == 0) {
            float a[8];
#pragma unroll
            for (int h = 0; h < 8; h++) {
                float zz = 0.f;
#pragma unroll
                for (int k = 0; k < 10; k++) zz = fmaf(hv[k], w2s[k * 10 + h], zz);
                a[h] = zz;
            }
            float4* Ar = reinterpret_cast<float4*>(An + (size_t)n * RS);
            Ar[0] = make_float4(a[0], a[1], a[2], a[3]);
            Ar[1] = make_float4(a[4], a[5], a[6], a[7]);
        } else if (q == 1) {
            float a8 = 0.f, a9 = 0.f;
#pragma unroll
            for (int k = 0; k < 10; k++) {
                a8 = fmaf(hv[k], w2s[k * 10 + 8], a8);
                a9 = fmaf(hv[k], w2s[k * 10 + 9], a9);
            }
            *reinterpret_cast<float2*>(An + (size_t)n * RS + 8) = make_float2(a8, a9);
        } else if (q == 2) {
            float b[8];
#pragma unroll
            for (int h = 0; h < 8; h++) {
                float zz = 0.f;
#pragma unroll
                for (int k = 0; k < 10; k++) zz = fmaf(hv[k], w2s[100 + k * 10 + h], zz);
                b[h] = zz;
            }
            *reinterpret_cast<uint4*>(Bn + (size_t)n * BRS) =
                make_uint4(packbf2(b[0], b[1]), packbf2(b[2], b[3]),
                           packbf2(b[4], b[5]), packbf2(b[6], b[7]));
        } else {
            float b8 = 0.f, b9 = 0.f;
#pragma unroll
            for (int k = 0; k < 10; k++) {
                b8 = fmaf(hv[k], w2s[100 + k * 10 + 8], b8);
                b9 = fmaf(hv[k], w2s[100 + k * 10 + 9], b9);
            }
            Bn[(size_t)n * BRS + 4] = packbf2(b8, b9);
        }
    }
}

// ---------- Final node MLP (tiled): out = relu(relu(H@Wf1)@Wf2) ----------
__global__ __launch_bounds__(256) void final_k(
    const float* __restrict__ H,    // [NN,RS]
    const float* __restrict__ Wf1,  // [10,64]
    const float* __restrict__ Wf2,  // [64,64]
    float* __restrict__ out,        // [NN,64]
    int n_nodes)
{
    __shared__ float wf1[640];
    __shared__ float wf2s[64 * 64];
    __shared__ float tT[64 * 64];

    for (int i = threadIdx.x; i < 640; i += 256) wf1[i] = Wf1[i];
    {
        const float4* w2v = reinterpret_cast<const float4*>(Wf2);
        float4* w2s = reinterpret_cast<float4*>(wf2s);
        for (int i = threadIdx.x; i < 1024; i += 256) w2s[i] = w2v[i];
    }

    int node0 = blockIdx.x * 64;

    {
        int r = threadIdx.x & 63;
        int g = threadIdx.x >> 6;
        int node = node0 + r;
        float hv[10];
        if (node < n_nodes) {
            const float4* hr = reinterpret_cast<const float4*>(H + (size_t)node * RS);
            float4 h0 = hr[0], h1 = hr[1];
            float2 h2 = *reinterpret_cast<const float2*>(H + (size_t)node * RS + 8);
            hv[0]=h0.x; hv[1]=h0.y; hv[2]=h0.z; hv[3]=h0.w;
            hv[4]=h1.x; hv[5]=h1.y; hv[6]=h1.z; hv[7]=h1.w;
            hv[8]=h2.x; hv[9]=h2.y;
        } else {
#pragma unroll
            for (int k = 0; k < 10; k++) hv[k] = 0.f;
        }
        __syncthreads();
#pragma unroll
        for (int j = 0; j < 16; j++) {
            int c = g * 16 + j;
            float v = 0.f;
#pragma unroll
            for (int k = 0; k < 10; k++) v = fmaf(hv[k], wf1[k * 64 + c], v);
            tT[c * 64 + r] = fmaxf(v, 0.f);
        }
    }
    __syncthreads();

    int r0 = (threadIdx.x >> 4) * 4;
    int c0 = (threadIdx.x & 15) * 4;
    float acc[4][4];
#pragma unroll
    for (int i = 0; i < 4; i++)
#pragma unroll
        for (int j = 0; j < 4; j++) acc[i][j] = 0.f;

    for (int k = 0; k < 64; k++) {
        float4 a = *reinterpret_cast<const float4*>(&tT[k * 64 + r0]);
        float4 b = *reinterpret_cast<const float4*>(&wf2s[k * 64 + c0]);
        float av[4] = { a.x, a.y, a.z, a.w };
        float bv[4] = { b.x, b.y, b.z, b.w };
#pragma unroll
        for (int i = 0; i < 4; i++)
#pragma unroll
            for (int j = 0; j < 4; j++)
                acc[i][j] = fmaf(av[i], bv[j], acc[i][j]);
    }

#pragma unroll
    for (int i = 0; i < 4; i++) {
        int node = node0 + r0 + i;
        if (node < n_nodes) {
            float4 o = make_float4(fmaxf(acc[i][0], 0.f), fmaxf(acc[i][1], 0.f),
                                   fmaxf(acc[i][2], 0.f), fmaxf(acc[i][3], 0.f));
            *reinterpret_cast<float4*>(&out[(size_t)node * FEAT + c0]) = o;
        }
    }
}

extern "C" void kernel_launch(void* const* d_in, const int* in_sizes, int n_in,
                              void* d_out, int out_size, void* d_ws, size_t ws_size,
                              hipStream_t stream) {
    const float* X    = (const float*)d_in[0];
    const float* W2_0 = (const float*)d_in[1];
    const float* W1_0 = (const float*)d_in[2];
    const float* W2_1 = (const float*)d_in[3];
    const float* W1_1 = (const float*)d_in[4];
    const float* W2_2 = (const float*)d_in[5];
    const float* W1_2 = (const float*)d_in[6];
    const float* Wf1  = (const float*)d_in[7];
    const float* Wf2  = (const float*)d_in[8];
    const int* src = (const int*)d_in[9];
    const int* dst = (const int*)d_in[10];
    float* out = (float*)d_out;

    const int n_edges = in_sizes[9];
    const int n_nodes = in_sizes[0] / FEAT;

    const int nbk  = (n_nodes + 63) >> 6;          // coarse buckets (<=2048 for scan_k)
    const int nblk = (n_edges + EPB - 1) / EPB;    // binning blocks (~1221)
    const int nchk = (nblk + CHK - 1) / CHK;       // column-prefix chunks (~39)

    const size_t h_elems = (size_t)n_nodes * RS;
    const size_t b_elems = (size_t)n_nodes * BRS;
    // ws layout (4B elems): H | A0 | A1 | B0 | B1 | nbr | packed | blockhist | chunksum | btot | bbase | bstart | start
    const size_t offH   = 0;
    const size_t offA0  = offH  + h_elems;
    const size_t offA1  = offA0 + h_elems;
    const size_t offB0  = offA1 + h_elems;
    const size_t offB1  = offB0 + b_elems;
    const size_t offNbr = offB1 + b_elems;
    const size_t offPk  = offNbr + (size_t)n_edges;
    const size_t offBh  = offPk + (size_t)n_edges;
    const size_t offCs  = offBh + (size_t)nblk * nbk;
    const size_t offBt  = offCs + (size_t)nbk * nchk;
    const size_t offBb  = offBt + (size_t)nbk;
    const size_t offBs  = offBb + (size_t)nbk;
    const size_t offSt  = offBs + (size_t)nbk + 1;

    float* H            = (float*)d_ws + offH;
    float* A0           = (float*)d_ws + offA0;
    float* A1           = (float*)d_ws + offA1;
    unsigned int* B0    = (unsigned int*)d_ws + offB0;
    unsigned int* B1    = (unsigned int*)d_ws + offB1;
    int* nbr            = (int*)d_ws + offNbr;
    int* packed         = (int*)d_ws + offPk;
    int* blockhist      = (int*)d_ws + offBh;
    int* chunksum       = (int*)d_ws + offCs;
    int* btot           = (int*)d_ws + offBt;
    int* bbase          = (int*)d_ws + offBb;
    int* bstart         = (int*)d_ws + offBs;
    int* start          = (int*)d_ws + offSt;

    const int nb = (n_nodes + 255) / 256;
    const int gb = (n_nodes * 4 + 255) / 256;
    const int fb = (n_nodes + 63) / 64;
    const int cb = (nbk + 255) / 256;
    const size_t lds_bins = (size_t)nbk * 4;

    // ---- CSR build ----
    bin_hist_k<<<nblk, 256, lds_bins, stream>>>(dst, blockhist, n_edges, nbk);
    colchunk_sum_k<<<dim3(cb, nchk), 256, 0, stream>>>(blockhist, chunksum, nbk, nblk, nchk);
    chunk_scan_k<<<cb, 256, 0, stream>>>(chunksum, btot, nbk, nchk);
    scan_k<<<1, 256, 0, stream>>>(btot, bbase, bstart, start, nbk, n_nodes, n_edges);
    col_off2_k<<<dim3(cb, nchk), 256, 0, stream>>>(blockhist, chunksum, bbase, nbk, nblk, nchk);
    bin_scatter_k<<<nblk, 256, lds_bins, stream>>>(src, dst, blockhist, packed, n_edges, nbk);
    csr_k<<<nbk, 256, 0, stream>>>(packed, bstart, nbr, start, n_nodes);

    // ---- Layer 0 precompute + 3 fused gather layers ----
    pre_l0<<<nb, 256, 0, stream>>>(X, W2_0, A0, B0, n_nodes);
    gather_k<false><<<gb, 256, 0, stream>>>(A0, B0, W1_0, W2_1, start, nbr,
                                            A1, B1, nullptr, n_nodes);
    gather_k<false><<<gb, 256, 0, stream>>>(A1, B1, W1_1, W2_2, start, nbr,
                                            A0, B0, nullptr, n_nodes);
    gather_k<true><<<gb, 256, 0, stream>>>(A0, B0, W1_2, nullptr, start, nbr,
                                           nullptr, nullptr, H, n_nodes);

    // ---- Final node MLP ----
    final_k<<<fb, 256, 0, stream>>>(H, Wf1, Wf2, out, n_nodes);
}

// Round 11
// 249.300 us; speedup vs baseline: 1.6880x; 1.0027x over previous
//
#include <hip/hip_runtime.h>
#include <hip/hip_bf16.h>
#include <hip/hip_fp16.h>

#define FEAT 64
#define HID 10
#define RS 16    // fp32 row stride (floats) -> 64B rows
#define BRS 4    // packed-fp12 B row stride (dwords) -> 16B rows, ONE dwordx4 per edge
#define EPB 1024 // edges per block in binning passes -> ~1221 blocks
#define BSH 6    // bucket shift: 64 nodes per bucket
#define CHK 32   // block-rows per chunk in column-prefix passes

typedef __attribute__((ext_vector_type(2))) float f32x2;

#if defined(__has_builtin)
#if __has_builtin(__builtin_elementwise_fma)
#define HAVE_EW_FMA 1
#endif
#endif

__device__ __forceinline__ f32x2 pk_fma(f32x2 a, f32x2 b, f32x2 c) {
#ifdef HAVE_EW_FMA
    return __builtin_elementwise_fma(a, b, c);
#else
    f32x2 r; r.x = fmaf(a.x, b.x, c.x); r.y = fmaf(a.y, b.y, c.y); return r;
#endif
}
__device__ __forceinline__ f32x2 pk_max0(f32x2 a) {
    f32x2 r; r.x = fmaxf(a.x, 0.f); r.y = fmaxf(a.y, 0.f); return r;
}

// ---- fp12 (s1e5m6 = top 12 bits of fp16, RTN) codec ----
__device__ __forceinline__ unsigned int f2fp12(float v) {
    unsigned short h = __half_as_ushort(__float2half(v));
    return (((unsigned int)h) + 8u) >> 4;   // round-to-nearest into 12 bits
}
__device__ __forceinline__ float fp12f(unsigned int f) {
    return __half2float(__ushort_as_half((unsigned short)(f << 4)));
}
// pack 10 fp12 fields into 4 dwords
__device__ __forceinline__ uint4 pack10(const float* b) {
    unsigned int f[10];
#pragma unroll
    for (int i = 0; i < 10; i++) f[i] = f2fp12(b[i]);
    uint4 d;
    d.x = f[0] | (f[1] << 12) | (f[2] << 24);
    d.y = (f[2] >> 8) | (f[3] << 4) | (f[4] << 16) | (f[5] << 28);
    d.z = (f[5] >> 4) | (f[6] << 8) | (f[7] << 20);
    d.w = f[8] | (f[9] << 12);
    return d;
}

// ---------- Layer-0 precompute: A=X@W2[0:64,:] (fp32), B=X@W2[64:128,:] (fp12 packed) ----------
__global__ __launch_bounds__(256) void pre_l0(
    const float* __restrict__ X,    // [NN,64]
    const float* __restrict__ W2,   // [128,10]
    float* __restrict__ A,          // [NN,RS] fp32
    unsigned int* __restrict__ Bt,  // [NN,BRS] packed fp12
    int n_nodes)
{
    __shared__ float w2[128 * 10];
    for (int i = threadIdx.x; i < 1280; i += 256) w2[i] = W2[i];
    __syncthreads();

    int n = blockIdx.x * 256 + threadIdx.x;
    if (n >= n_nodes) return;

    const float4* xr = reinterpret_cast<const float4*>(X + (size_t)n * FEAT);
    float a[10], b[10];
#pragma unroll
    for (int h = 0; h < 10; h++) { a[h] = 0.f; b[h] = 0.f; }

#pragma unroll
    for (int blk = 0; blk < 16; blk++) {
        float4 u = xr[blk];
        float xv[4] = { u.x, u.y, u.z, u.w };
#pragma unroll
        for (int j = 0; j < 4; j++) {
            int k = blk * 4 + j;
#pragma unroll
            for (int h = 0; h < 10; h++) {
                a[h] = fmaf(xv[j], w2[k * 10 + h], a[h]);
                b[h] = fmaf(xv[j], w2[(64 + k) * 10 + h], b[h]);
            }
        }
    }

    float4* Ar = reinterpret_cast<float4*>(A + (size_t)n * RS);
    Ar[0] = make_float4(a[0], a[1], a[2], a[3]);
    Ar[1] = make_float4(a[4], a[5], a[6], a[7]);
    Ar[2] = make_float4(a[8], a[9], 0.f, 0.f);
    *reinterpret_cast<uint4*>(Bt + (size_t)n * BRS) = pack10(b);
}

// ================= CSR build: two-level counting sort, LDS cursors only =================

__global__ __launch_bounds__(256) void bin_hist_k(
    const int* __restrict__ dst, int* __restrict__ blockhist, int n_edges, int nbk)
{
    extern __shared__ int hist[];
    for (int i = threadIdx.x; i < nbk; i += 256) hist[i] = 0;
    __syncthreads();
    int base = blockIdx.x * EPB;
    for (int i = threadIdx.x; i < EPB; i += 256) {
        int e = base + i;
        if (e < n_edges) atomicAdd(&hist[dst[e] >> BSH], 1);
    }
    __syncthreads();
    int* row = blockhist + (size_t)blockIdx.x * nbk;
    for (int i = threadIdx.x; i < nbk; i += 256) row[i] = hist[i];
}

// chunksum is stored TRANSPOSED: chunksum[b * nchk + c]
__global__ __launch_bounds__(256) void colchunk_sum_k(
    const int* __restrict__ blockhist, int* __restrict__ chunksum,
    int nbk, int nblk, int nchk)
{
    int b = blockIdx.x * 256 + threadIdx.x;
    int c = blockIdx.y;
    if (b >= nbk) return;
    int k0 = c * CHK;
    int k1 = min(k0 + CHK, nblk);
    int s = 0;
    for (int k = k0; k < k1; k++) s += blockhist[(size_t)k * nbk + b];
    chunksum[(size_t)b * nchk + c] = s;
}

__global__ __launch_bounds__(256) void chunk_scan_k(
    int* __restrict__ chunksum, int* __restrict__ btot, int nbk, int nchk)
{
    int b = blockIdx.x * 256 + threadIdx.x;
    if (b >= nbk) return;
    int run = 0;
    int* row = chunksum + (size_t)b * nchk;
    for (int c = 0; c < nchk; c++) {
        int v = row[c];
        row[c] = run;
        run += v;
    }
    btot[b] = run;
}

__global__ __launch_bounds__(256) void scan_k(
    const int* __restrict__ btot, int* __restrict__ bbase,
    int* __restrict__ bucket_start, int* __restrict__ start,
    int nbk, int n_nodes, int n_edges)
{
    __shared__ int ts[256];
    int t = threadIdx.x;
    int v[8];
    int s = 0;
#pragma unroll
    for (int j = 0; j < 8; j++) {
        int idx = t * 8 + j;
        v[j] = (idx < nbk) ? btot[idx] : 0;
        s += v[j];
    }
    ts[t] = s;
    __syncthreads();
    for (int off = 1; off < 256; off <<= 1) {
        int x = (t >= off) ? ts[t - off] : 0;
        __syncthreads();
        ts[t] += x;
        __syncthreads();
    }
    int run = ts[t] - s;
#pragma unroll
    for (int j = 0; j < 8; j++) {
        int idx = t * 8 + j;
        if (idx < nbk) { bbase[idx] = run; bucket_start[idx] = run; }
        run += v[j];
    }
    if (t == 255) { bucket_start[nbk] = n_edges; start[n_nodes] = n_edges; }
}

__global__ __launch_bounds__(256) void col_off2_k(
    int* __restrict__ blockhist, const int* __restrict__ chunksum,
    const int* __restrict__ bbase, int nbk, int nblk, int nchk)
{
    int b = blockIdx.x * 256 + threadIdx.x;
    int c = blockIdx.y;
    if (b >= nbk) return;
    int k0 = c * CHK;
    int k1 = min(k0 + CHK, nblk);
    int run = bbase[b] + chunksum[(size_t)b * nchk + c];
    for (int k = k0; k < k1; k++) {
        size_t idx = (size_t)k * nbk + b;
        int v = blockhist[idx];
        blockhist[idx] = run;
        run += v;
    }
}

__global__ __launch_bounds__(256) void bin_scatter_k(
    const int* __restrict__ src, const int* __restrict__ dst,
    const int* __restrict__ blockhist, int* __restrict__ packed,
    int n_edges, int nbk)
{
    extern __shared__ int cur[];
    const int* row = blockhist + (size_t)blockIdx.x * nbk;
    for (int i = threadIdx.x; i < nbk; i += 256) cur[i] = row[i];
    __syncthreads();
    int base = blockIdx.x * EPB;
    for (int i = threadIdx.x; i < EPB; i += 256) {
        int e = base + i;
        if (e < n_edges) {
            int d = dst[e];
            int pos = atomicAdd(&cur[d >> BSH], 1);
            packed[pos] = ((d & 63) << 17) | src[e];
        }
    }
}

__global__ __launch_bounds__(256) void csr_k(
    const int* __restrict__ packed, const int* __restrict__ bucket_start,
    int* __restrict__ nbr, int* __restrict__ start, int n_nodes)
{
    __shared__ int hist[64];
    __shared__ int excl[64];
    __shared__ int cur[64];
    int b = blockIdx.x;
    int base = bucket_start[b];
    int end  = bucket_start[b + 1];
    if (threadIdx.x < 64) hist[threadIdx.x] = 0;
    __syncthreads();
    for (int i = base + threadIdx.x; i < end; i += 256)
        atomicAdd(&hist[packed[i] >> 17], 1);
    __syncthreads();
    if (threadIdx.x == 0) {
        int r = 0;
        for (int k = 0; k < 64; k++) { excl[k] = r; r += hist[k]; }
    }
    __syncthreads();
    if (threadIdx.x < 64) {
        cur[threadIdx.x] = excl[threadIdx.x];
        int node = (b << 6) + threadIdx.x;
        if (node < n_nodes) start[node] = base + excl[threadIdx.x];
    }
    __syncthreads();
    for (int i = base + threadIdx.x; i < end; i += 256) {
        int p = packed[i];
        int pos = base + atomicAdd(&cur[p >> 17], 1);
        nbr[pos] = p & 0x1FFFF;
    }
}

// ---------- Gather-aggregate (quad-per-node, ONE dwordx4 per edge, fused next-layer pre) ----------
// h = 0.1 * sum_in relu(relu(A[n] + B[s]) @ W1)
// LAST ? Hout[n] = h : { An[n] = h@W2n[0:10], Bn[n] = pack_fp12(h@W2n[10:20]) }
template<bool LAST>
__global__ __launch_bounds__(256) void gather_k(
    const float* __restrict__ A,           // [NN,RS] fp32
    const unsigned int* __restrict__ Bt,   // [NN,BRS] packed fp12
    const float* __restrict__ W1,          // [10,10] -> SGPR pairs
    const float* __restrict__ W2n,         // [20,10] (LDS; unused if LAST)
    const int* __restrict__ start,         // [NN+1]
    const int* __restrict__ nbr,           // [NE]
    float* __restrict__ An,                // fp32 next-A (unused if LAST)
    unsigned int* __restrict__ Bn,         // packed next-B (unused if LAST)
    float* __restrict__ Hout,              // fp32 H (used if LAST)
    int n_nodes)
{
    __shared__ float w2s[200];
    if (!LAST) {
        for (int i = threadIdx.x; i < 200; i += 256) w2s[i] = W2n[i];
        __syncthreads();
    }

    // W1 as float2 pairs; uniform loads -> SGPRs.
    f32x2 w1p[10][5];
#pragma unroll
    for (int j = 0; j < 10; j++)
#pragma unroll
        for (int h2 = 0; h2 < 5; h2++)
            w1p[j][h2] = (f32x2){ W1[j * 10 + 2 * h2], W1[j * 10 + 2 * h2 + 1] };

    int t = blockIdx.x * 256 + threadIdx.x;
    int n = t >> 2;
    int q = t & 3;
    if (n >= n_nodes) return;

    const float4* ar = reinterpret_cast<const float4*>(A + (size_t)n * RS);
    float4 a0 = ar[0], a1 = ar[1], a2 = ar[2];
    f32x2 av2[5] = { {a0.x,a0.y}, {a0.z,a0.w}, {a1.x,a1.y}, {a1.z,a1.w}, {a2.x,a2.y} };

    f32x2 acc2[5];
#pragma unroll
    for (int h2 = 0; h2 < 5; h2++) acc2[h2] = (f32x2){0.f, 0.f};

    int beg = start[n];
    int end = start[n + 1];
    for (int i = beg + q; i < end; i += 4) {
        int s = nbr[i];
        uint4 d = *reinterpret_cast<const uint4*>(Bt + (size_t)s * BRS);  // single VMEM op
        // decode 10 fp12 fields
        unsigned int f0 = d.x & 0xFFFu;
        unsigned int f1 = (d.x >> 12) & 0xFFFu;
        unsigned int f2 = (d.x >> 24) | ((d.y & 0xFu) << 8);
        unsigned int f3 = (d.y >> 4) & 0xFFFu;
        unsigned int f4 = (d.y >> 16) & 0xFFFu;
        unsigned int f5 = ((d.y >> 28) & 0xFu) | ((d.z & 0xFFu) << 4);
        unsigned int f6 = (d.z >> 8) & 0xFFFu;
        unsigned int f7 = d.z >> 20;
        unsigned int f8 = d.w & 0xFFFu;
        unsigned int f9 = (d.w >> 12) & 0xFFFu;

        f32x2 pre[5];
        pre[0] = av2[0] + (f32x2){ fp12f(f0), fp12f(f1) };
        pre[1] = av2[1] + (f32x2){ fp12f(f2), fp12f(f3) };
        pre[2] = av2[2] + (f32x2){ fp12f(f4), fp12f(f5) };
        pre[3] = av2[3] + (f32x2){ fp12f(f6), fp12f(f7) };
        pre[4] = av2[4] + (f32x2){ fp12f(f8), fp12f(f9) };
#pragma unroll
        for (int k = 0; k < 5; k++) pre[k] = pk_max0(pre[k]);

        f32x2 z[5];
#pragma unroll
        for (int h2 = 0; h2 < 5; h2++) z[h2] = (f32x2){0.f, 0.f};
#pragma unroll
        for (int j2 = 0; j2 < 5; j2++) {
            f32x2 pa = (f32x2){ pre[j2].x, pre[j2].x };
            f32x2 pb = (f32x2){ pre[j2].y, pre[j2].y };
#pragma unroll
            for (int h2 = 0; h2 < 5; h2++) {
                z[h2] = pk_fma(pa, w1p[2 * j2][h2], z[h2]);
                z[h2] = pk_fma(pb, w1p[2 * j2 + 1][h2], z[h2]);
            }
        }
#pragma unroll
        for (int h2 = 0; h2 < 5; h2++) acc2[h2] += pk_max0(z[h2]);
    }

    // quad reduction: after xor1+xor2 ALL 4 lanes hold the full sum
#pragma unroll
    for (int h2 = 0; h2 < 5; h2++) {
        acc2[h2].x += __shfl_xor(acc2[h2].x, 1);
        acc2[h2].y += __shfl_xor(acc2[h2].y, 1);
    }
#pragma unroll
    for (int h2 = 0; h2 < 5; h2++) {
        acc2[h2].x += __shfl_xor(acc2[h2].x, 2);
        acc2[h2].y += __shfl_xor(acc2[h2].y, 2);
    }

    float hv[10];
#pragma unroll
    for (int h2 = 0; h2 < 5; h2++) {
        hv[2 * h2]     = acc2[h2].x * 0.1f;
        hv[2 * h2 + 1] = acc2[h2].y * 0.1f;
    }

    if (LAST) {
        float* Hr = Hout + (size_t)n * RS;
        if (q == 0)      *reinterpret_cast<float4*>(Hr)     = make_float4(hv[0], hv[1], hv[2], hv[3]);
        else if (q == 1) *reinterpret_cast<float4*>(Hr + 4) = make_float4(hv[4], hv[5], hv[6], hv[7]);
        else if (q == 2) *reinterpret_cast<float2*>(Hr + 8) = make_float2(hv[8], hv[9]);
    } else {
        if (q == 0) {
            float a[8];
#pragma unroll
            for (int h = 0; h < 8; h++) {
                float zz = 0.f;
#pragma unroll
                for (int k = 0; k < 10; k++) zz = fmaf(hv[k], w2s[k * 10 + h], zz);
                a[h] = zz;
            }
            float4* Ar = reinterpret_cast<float4*>(An + (size_t)n * RS);
            Ar[0] = make_float4(a[0], a[1], a[2], a[3]);
            Ar[1] = make_float4(a[4], a[5], a[6], a[7]);
        } else if (q == 1) {
            float a8 = 0.f, a9 = 0.f;
#pragma unroll
            for (int k = 0; k < 10; k++) {
                a8 = fmaf(hv[k], w2s[k * 10 + 8], a8);
                a9 = fmaf(hv[k], w2s[k * 10 + 9], a9);
            }
            *reinterpret_cast<float2*>(An + (size_t)n * RS + 8) = make_float2(a8, a9);
        } else if (q == 2) {
            float b[10];
#pragma unroll
            for (int h = 0; h < 10; h++) {
                float zz = 0.f;
#pragma unroll
                for (int k = 0; k < 10; k++) zz = fmaf(hv[k], w2s[100 + k * 10 + h], zz);
                b[h] = zz;
            }
            *reinterpret_cast<uint4*>(Bn + (size_t)n * BRS) = pack10(b);
        }
        // q == 3: idle in epilogue
    }
}

// ---------- Final node MLP (tiled): out = relu(relu(H@Wf1)@Wf2) ----------
__global__ __launch_bounds__(256) void final_k(
    const float* __restrict__ H,    // [NN,RS]
    const float* __restrict__ Wf1,  // [10,64]
    const float* __restrict__ Wf2,  // [64,64]
    float* __restrict__ out,        // [NN,64]
    int n_nodes)
{
    __shared__ float wf1[640];
    __shared__ float wf2s[64 * 64];
    __shared__ float tT[64 * 64];

    for (int i = threadIdx.x; i < 640; i += 256) wf1[i] = Wf1[i];
    {
        const float4* w2v = reinterpret_cast<const float4*>(Wf2);
        float4* w2s = reinterpret_cast<float4*>(wf2s);
        for (int i = threadIdx.x; i < 1024; i += 256) w2s[i] = w2v[i];
    }

    int node0 = blockIdx.x * 64;

    {
        int r = threadIdx.x & 63;
        int g = threadIdx.x >> 6;
        int node = node0 + r;
        float hv[10];
        if (node < n_nodes) {
            const float4* hr = reinterpret_cast<const float4*>(H + (size_t)node * RS);
            float4 h0 = hr[0], h1 = hr[1];
            float2 h2 = *reinterpret_cast<const float2*>(H + (size_t)node * RS + 8);
            hv[0]=h0.x; hv[1]=h0.y; hv[2]=h0.z; hv[3]=h0.w;
            hv[4]=h1.x; hv[5]=h1.y; hv[6]=h1.z; hv[7]=h1.w;
            hv[8]=h2.x; hv[9]=h2.y;
        } else {
#pragma unroll
            for (int k = 0; k < 10; k++) hv[k] = 0.f;
        }
        __syncthreads();
#pragma unroll
        for (int j = 0; j < 16; j++) {
            int c = g * 16 + j;
            float v = 0.f;
#pragma unroll
            for (int k = 0; k < 10; k++) v = fmaf(hv[k], wf1[k * 64 + c], v);
            tT[c * 64 + r] = fmaxf(v, 0.f);
        }
    }
    __syncthreads();

    int r0 = (threadIdx.x >> 4) * 4;
    int c0 = (threadIdx.x & 15) * 4;
    float acc[4][4];
#pragma unroll
    for (int i = 0; i < 4; i++)
#pragma unroll
        for (int j = 0; j < 4; j++) acc[i][j] = 0.f;

    for (int k = 0; k < 64; k++) {
        float4 a = *reinterpret_cast<const float4*>(&tT[k * 64 + r0]);
        float4 b = *reinterpret_cast<const float4*>(&wf2s[k * 64 + c0]);
        float av[4] = { a.x, a.y, a.z, a.w };
        float bv[4] = { b.x, b.y, b.z, b.w };
#pragma unroll
        for (int i = 0; i < 4; i++)
#pragma unroll
            for (int j = 0; j < 4; j++)
                acc[i][j] = fmaf(av[i], bv[j], acc[i][j]);
    }

#pragma unroll
    for (int i = 0; i < 4; i++) {
        int node = node0 + r0 + i;
        if (node < n_nodes) {
            float4 o = make_float4(fmaxf(acc[i][0], 0.f), fmaxf(acc[i][1], 0.f),
                                   fmaxf(acc[i][2], 0.f), fmaxf(acc[i][3], 0.f));
            *reinterpret_cast<float4*>(&out[(size_t)node * FEAT + c0]) = o;
        }
    }
}

extern "C" void kernel_launch(void* const* d_in, const int* in_sizes, int n_in,
                              void* d_out, int out_size, void* d_ws, size_t ws_size,
                              hipStream_t stream) {
    const float* X    = (const float*)d_in[0];
    const float* W2_0 = (const float*)d_in[1];
    const float* W1_0 = (const float*)d_in[2];
    const float* W2_1 = (const float*)d_in[3];
    const float* W1_1 = (const float*)d_in[4];
    const float* W2_2 = (const float*)d_in[5];
    const float* W1_2 = (const float*)d_in[6];
    const float* Wf1  = (const float*)d_in[7];
    const float* Wf2  = (const float*)d_in[8];
    const int* src = (const int*)d_in[9];
    const int* dst = (const int*)d_in[10];
    float* out = (float*)d_out;

    const int n_edges = in_sizes[9];
    const int n_nodes = in_sizes[0] / FEAT;

    const int nbk  = (n_nodes + 63) >> 6;          // coarse buckets (<=2048 for scan_k)
    const int nblk = (n_edges + EPB - 1) / EPB;    // binning blocks (~1221)
    const int nchk = (nblk + CHK - 1) / CHK;       // column-prefix chunks (~39)

    const size_t h_elems = (size_t)n_nodes * RS;
    const size_t b_elems = (size_t)n_nodes * BRS;
    // ws layout (4B elems): H | A0 | A1 | B0 | B1 | nbr | packed | blockhist | chunksum | btot | bbase | bstart | start
    const size_t offH   = 0;
    const size_t offA0  = offH  + h_elems;
    const size_t offA1  = offA0 + h_elems;
    const size_t offB0  = offA1 + h_elems;
    const size_t offB1  = offB0 + b_elems;
    const size_t offNbr = offB1 + b_elems;
    const size_t offPk  = offNbr + (size_t)n_edges;
    const size_t offBh  = offPk + (size_t)n_edges;
    const size_t offCs  = offBh + (size_t)nblk * nbk;
    const size_t offBt  = offCs + (size_t)nbk * nchk;
    const size_t offBb  = offBt + (size_t)nbk;
    const size_t offBs  = offBb + (size_t)nbk;
    const size_t offSt  = offBs + (size_t)nbk + 1;

    float* H            = (float*)d_ws + offH;
    float* A0           = (float*)d_ws + offA0;
    float* A1           = (float*)d_ws + offA1;
    unsigned int* B0    = (unsigned int*)d_ws + offB0;
    unsigned int* B1    = (unsigned int*)d_ws + offB1;
    int* nbr            = (int*)d_ws + offNbr;
    int* packed         = (int*)d_ws + offPk;
    int* blockhist      = (int*)d_ws + offBh;
    int* chunksum       = (int*)d_ws + offCs;
    int* btot           = (int*)d_ws + offBt;
    int* bbase          = (int*)d_ws + offBb;
    int* bstart         = (int*)d_ws + offBs;
    int* start          = (int*)d_ws + offSt;

    const int nb = (n_nodes + 255) / 256;
    const int gb = (n_nodes * 4 + 255) / 256;
    const int fb = (n_nodes + 63) / 64;
    const int cb = (nbk + 255) / 256;
    const size_t lds_bins = (size_t)nbk * 4;

    // ---- CSR build ----
    bin_hist_k<<<nblk, 256, lds_bins, stream>>>(dst, blockhist, n_edges, nbk);
    colchunk_sum_k<<<dim3(cb, nchk), 256, 0, stream>>>(blockhist, chunksum, nbk, nblk, nchk);
    chunk_scan_k<<<cb, 256, 0, stream>>>(chunksum, btot, nbk, nchk);
    scan_k<<<1, 256, 0, stream>>>(btot, bbase, bstart, start, nbk, n_nodes, n_edges);
    col_off2_k<<<dim3(cb, nchk), 256, 0, stream>>>(blockhist, chunksum, bbase, nbk, nblk, nchk);
    bin_scatter_k<<<nblk, 256, lds_bins, stream>>>(src, dst, blockhist, packed, n_edges, nbk);
    csr_k<<<nbk, 256, 0, stream>>>(packed, bstart, nbr, start, n_nodes);

    // ---- Layer 0 precompute + 3 fused gather layers ----
    pre_l0<<<nb, 256, 0, stream>>>(X, W2_0, A0, B0, n_nodes);
    gather_k<false><<<gb, 256, 0, stream>>>(A0, B0, W1_0, W2_1, start, nbr,
                                            A1, B1, nullptr, n_nodes);
    gather_k<false><<<gb, 256, 0, stream>>>(A1, B1, W1_1, W2_2, start, nbr,
                                            A0, B0, nullptr, n_nodes);
    gather_k<true><<<gb, 256, 0, stream>>>(A0, B0, W1_2, nullptr, start, nbr,
                                           nullptr, nullptr, H, n_nodes);

    // ---- Final node MLP ----
    final_k<<<fb, 256, 0, stream>>>(H, Wf1, Wf2, out, n_nodes);
}